// Round 9
// baseline (87.486 us; speedup 1.0000x reference)
//
#include <hip/hip_runtime.h>
#include <stdint.h>

// Trilinear resampler, REPLICATE (clamp) boundary.
// Counting-sort points into 8x8x16 voxel tiles (no global atomics, 8B packed
// records, u16 block histograms), then one 256-thread block per tile stages
// the tile's 8 z-planes + y/x halo (8x9x17) into LDS as bf16 and samples its
// points from LDS. Points whose upper-z corner falls in the next z-plane
// (lz==7, ~12.5%) read those 4 corners from global fp32 (L2-hot, same XCD).
// z-halo-free staging -> 19.6 KB LDS -> 8 blocks/CU (32 waves, full cap).
// inputs:  [B, D, H, W, C] fp32   (B=2, D=H=W=128, C=8)
// coords:  [B, GD, GH, GW, 3] fp32, order (d, h, w)
// output:  [B, GD, GH, GW, C] fp32

constexpr int B  = 2;
constexpr int D  = 128;
constexpr int H  = 128;
constexpr int W  = 128;
constexpr int C  = 8;
constexpr int GD = 96;
constexpr int GH = 96;
constexpr int GW = 96;
constexpr long long PTS_PER_B = (long long)GD * GH * GW;   // 884736
constexpr long long NPTS      = (long long)B * PTS_PER_B;  // 1769472
constexpr int NPTS_I = (int)NPTS;                          // < 2^21

// tiles: 8 x 8 x 16 voxels (z,y,x)
constexpr int TPZ = 16, TPY = 16, TPX = 8;
constexpr int NT_PER_B = TPZ * TPY * TPX;       // 2048
constexpr int NT = B * NT_PER_B;                // 4096

// staged region: 8 z-planes (NO z halo) x (8+1) y x (16+1) x
constexpr int SRZ = 8, RY = 9, RX = 17;
constexpr int RVOX = SRZ * RY * RX;             // 1224 voxels * 16B = 19584 B

constexpr int TPB_BIN = 1024;
constexpr int PPT     = 8;
constexpr int NB_BIN  = NPTS_I / (TPB_BIN * PPT);   // 216
static_assert(NB_BIN * TPB_BIN * PPT == NPTS_I, "exact tiling");
constexpr int BPT = NT / TPB_BIN;               // 4

__device__ __forceinline__ int clampi(int v, int lo, int hi) {
    return min(max(v, lo), hi);
}

// packed record: [0,21) idx | [21,35) qx (14b) | [35,48) qy (13b) | [48,61) qz (13b)
// q* = local coord within tile in 1/1024 voxel units
__device__ __forceinline__ unsigned long long
pack_rec(int i, float zc, float yc, float xc, int b, int& tk)
{
    const int z0 = clampi((int)floorf(zc), 0, D - 1);
    const int y0 = clampi((int)floorf(yc), 0, H - 1);
    const int x0 = clampi((int)floorf(xc), 0, W - 1);
    const int tz = z0 >> 3, ty = y0 >> 3, tx = x0 >> 4;
    tk = (b << 11) | (tz << 7) | (ty << 3) | tx;
    const int qz = clampi((int)((zc - (float)(tz << 3)) * 1024.0f + 0.5f), 0,  8191);
    const int qy = clampi((int)((yc - (float)(ty << 3)) * 1024.0f + 0.5f), 0,  8191);
    const int qx = clampi((int)((xc - (float)(tx << 4)) * 1024.0f + 0.5f), 0, 16383);
    return (unsigned long long)(uint32_t)i
         | ((unsigned long long)qx << 21)
         | ((unsigned long long)qy << 35)
         | ((unsigned long long)qz << 48);
}

__device__ __forceinline__ int tile_of(int b, float zc, float yc, float xc) {
    int z0 = clampi((int)floorf(zc), 0, D - 1);
    int y0 = clampi((int)floorf(yc), 0, H - 1);
    int x0 = clampi((int)floorf(xc), 0, W - 1);
    return (b << 11) | ((z0 >> 3) << 7) | ((y0 >> 3) << 3) | (x0 >> 4);
}

// round-to-nearest-even f32 -> bf16 (low 16 bits)
__device__ __forceinline__ uint32_t bf16_rne(float f) {
    uint32_t u = __float_as_uint(f);
    u += 0x7FFFu + ((u >> 16) & 1u);
    return u >> 16;
}
__device__ __forceinline__ uint32_t pack_bf16(float lo, float hi) {
    return bf16_rne(lo) | (bf16_rne(hi) << 16);
}

// ---- K1: per-block LDS histogram -> blockHist[block][NT] (u16) -------------
__global__ __launch_bounds__(TPB_BIN)
void k_hist(const float* __restrict__ coords, uint16_t* __restrict__ blockHist)
{
    __shared__ uint32_t h[NT];                  // 16 KB
    const int t = threadIdx.x;
#pragma unroll
    for (int j = 0; j < BPT; ++j) h[t + j * TPB_BIN] = 0u;
    __syncthreads();

    const int base = blockIdx.x * (TPB_BIN * PPT);
#pragma unroll
    for (int k = 0; k < PPT; ++k) {
        const int i = base + k * TPB_BIN + t;
        const float zc = coords[3 * i + 0];
        const float yc = coords[3 * i + 1];
        const float xc = coords[3 * i + 2];
        const int b = (i >= (int)PTS_PER_B) ? 1 : 0;
        atomicAdd(&h[tile_of(b, zc, yc, xc)], 1u);
    }
    __syncthreads();
#pragma unroll
    for (int j = 0; j < BPT; ++j) {
        const int c = t + j * TPB_BIN;
        blockHist[blockIdx.x * NT + c] = (uint16_t)h[c];
    }
}

// ---- K2a: per-bucket column prefix over block rows --------------------------
__global__ __launch_bounds__(128)
void k_scan_cols(uint16_t* __restrict__ blockHist, uint32_t* __restrict__ bucketTot)
{
    const int c = blockIdx.x * 128 + threadIdx.x;
    uint32_t acc = 0u;
#pragma unroll 8
    for (int r = 0; r < NB_BIN; ++r) {
        const int o = r * NT + c;
        const uint32_t v = blockHist[o];
        blockHist[o] = (uint16_t)acc;           // fits u16 (<= bucket total)
        acc += v;
    }
    bucketTot[c] = acc;
}

// ---- K2b: scan of bucket totals -> bucketBase ------------------------------
__global__ __launch_bounds__(TPB_BIN)
void k_scan_base(const uint32_t* __restrict__ bucketTot, uint32_t* __restrict__ bucketBase)
{
    __shared__ uint32_t ss[TPB_BIN];
    const int t = threadIdx.x;

    uint32_t l[BPT];
    uint32_t ls = 0u;
#pragma unroll
    for (int j = 0; j < BPT; ++j) {
        l[j] = bucketTot[t * BPT + j];
        ls += l[j];
    }
    ss[t] = ls;
    __syncthreads();
    for (int off = 1; off < TPB_BIN; off <<= 1) {
        const uint32_t v = (t >= off) ? ss[t - off] : 0u;
        __syncthreads();
        ss[t] += v;
        __syncthreads();
    }
    uint32_t basev = ss[t] - ls;
#pragma unroll
    for (int j = 0; j < BPT; ++j) {
        bucketBase[t * BPT + j] = basev;
        basev += l[j];
    }
    if (t == TPB_BIN - 1) bucketBase[NT] = (uint32_t)NPTS_I;
}

// ---- K3: scatter packed 8B records via LDS cursors --------------------------
__global__ __launch_bounds__(TPB_BIN)
void k_scatter(const float* __restrict__ coords,
               const uint16_t* __restrict__ blockHist,
               const uint32_t* __restrict__ bucketBase,
               unsigned long long* __restrict__ records)
{
    __shared__ uint32_t cur[NT];                // 16 KB
    const int t = threadIdx.x;
#pragma unroll
    for (int j = 0; j < BPT; ++j) {
        const int c = t + j * TPB_BIN;
        cur[c] = (uint32_t)blockHist[blockIdx.x * NT + c] + bucketBase[c];
    }
    __syncthreads();

    const int base = blockIdx.x * (TPB_BIN * PPT);
#pragma unroll
    for (int k = 0; k < PPT; ++k) {
        const int i = base + k * TPB_BIN + t;
        const float zc = coords[3 * i + 0];
        const float yc = coords[3 * i + 1];
        const float xc = coords[3 * i + 2];
        const int b = (i >= (int)PTS_PER_B) ? 1 : 0;
        int tk;
        const unsigned long long r = pack_rec(i, zc, yc, xc, b, tk);
        const uint32_t slot = atomicAdd(&cur[tk], 1u);   // LDS atomic
        records[slot] = r;
    }
}

// ---- K4: one block per bucket; z-halo-free LDS; records prefetched ---------
__global__ __launch_bounds__(256)
void k_sample_tiled(const float* __restrict__ inp,
                    const unsigned long long* __restrict__ records,
                    const uint32_t* __restrict__ bucketBase,
                    float* __restrict__ out)
{
    __shared__ uint4 tile[RVOX];                // 1224 * 16B = 19584 B
    const int t = threadIdx.x;

    // XCD-chunked swizzle: consecutive buckets land on the same XCD's L2;
    // z-neighbor (c+128) stays in the same 512-bucket chunk -> its region is
    // L2-hot for the lz==7 global-corner path. NT % 8 == 0 -> bijective.
    const int g = blockIdx.x;
    const int c = (g & 7) * (NT >> 3) + (g >> 3);

    // decode bucket -> (b, tz, ty, tx)
    const int tx = c & 7;
    const int ty = (c >> 3) & 15;
    const int tz = (c >> 7) & 15;
    const int b  = c >> 11;
    const int z0r = tz << 3, y0r = ty << 3, x0r = tx << 4;
    const bool top_tile = (tz == 15);
    // address part for global z1-plane reads (valid only when tz < 15)
    const int zpart = ((b << 7) | (z0r + 8)) << 14;

    // bucket range + early record prefetch (latency hides under staging)
    const uint32_t s = bucketBase[c];
    const uint32_t e = bucketBase[c + 1];
    const bool rv0 = (s + (uint32_t)t        < e);
    const bool rv1 = (s + (uint32_t)t + 256u < e);
    unsigned long long r0 = 0ull, r1 = 0ull;
    if (rv0) r0 = records[s + (uint32_t)t];
    if (rv1) r1 = records[s + (uint32_t)t + 256u];

    // stage 1224 voxels in rounds of 3 + 2 (keeps VGPR pressure low)
    {
        float4 a0[3], a1[3];
#pragma unroll
        for (int j = 0; j < 3; ++j) {
            const int v = t + j * 256;
            const int lz = v / (RY * RX);
            const int rr = v - lz * (RY * RX);
            const int ly = rr / RX;
            const int lx = rr - ly * RX;
            const int gy = min(y0r + ly, H - 1);
            const int gx = min(x0r + lx, W - 1);
            const int a = ((((b << 7) | (z0r + lz)) << 7 | gy) << 7 | gx) * C;
            a0[j] = *reinterpret_cast<const float4*>(inp + a);
            a1[j] = *reinterpret_cast<const float4*>(inp + a + 4);
        }
#pragma unroll
        for (int j = 0; j < 3; ++j) {
            const int v = t + j * 256;
            uint4 pk;
            pk.x = pack_bf16(a0[j].x, a0[j].y);
            pk.y = pack_bf16(a0[j].z, a0[j].w);
            pk.z = pack_bf16(a1[j].x, a1[j].y);
            pk.w = pack_bf16(a1[j].z, a1[j].w);
            tile[v] = pk;
        }
#pragma unroll
        for (int j = 3; j < 5; ++j) {
            const int v = t + j * 256;
            if (v < RVOX) {
                const int lz = v / (RY * RX);
                const int rr = v - lz * (RY * RX);
                const int ly = rr / RX;
                const int lx = rr - ly * RX;
                const int gy = min(y0r + ly, H - 1);
                const int gx = min(x0r + lx, W - 1);
                const int a = ((((b << 7) | (z0r + lz)) << 7 | gy) << 7 | gx) * C;
                a0[j - 3] = *reinterpret_cast<const float4*>(inp + a);
                a1[j - 3] = *reinterpret_cast<const float4*>(inp + a + 4);
            }
        }
#pragma unroll
        for (int j = 3; j < 5; ++j) {
            const int v = t + j * 256;
            if (v < RVOX) {
                uint4 pk;
                pk.x = pack_bf16(a0[j - 3].x, a0[j - 3].y);
                pk.y = pack_bf16(a0[j - 3].z, a0[j - 3].w);
                pk.z = pack_bf16(a1[j - 3].x, a1[j - 3].y);
                pk.w = pack_bf16(a1[j - 3].z, a1[j - 3].w);
                tile[v] = pk;
            }
        }
    }
    __syncthreads();

    auto sample = [&](unsigned long long r) {
        const int idx = (int)(r & 0x1FFFFFull);
        const int qx  = (int)((r >> 21) & 0x3FFFull);
        const int qy  = (int)((r >> 35) & 0x1FFFull);
        const int qz  = (int)((r >> 48) & 0x1FFFull);
        const int lx = qx >> 10, ly = qy >> 10, lz = qz >> 10;   // lz in [0,7]
        const float wx1 = (float)(qx & 1023) * (1.0f / 1024.0f), wx0 = 1.0f - wx1;
        const float wy1 = (float)(qy & 1023) * (1.0f / 1024.0f), wy0 = 1.0f - wy1;
        const float wz1 = (float)(qz & 1023) * (1.0f / 1024.0f), wz0 = 1.0f - wz1;

        const float wys[2] = {wy0, wy1};
        const float wxs[2] = {wx0, wx1};

        float a0 = 0.f, a1 = 0.f, a2 = 0.f, a3 = 0.f;
        float a4 = 0.f, a5 = 0.f, a6 = 0.f, a7 = 0.f;

        auto lds_corner = [&](int cv, float wt) {
            const uint4 rv = tile[cv];
            a0 += wt * __uint_as_float(rv.x << 16);
            a1 += wt * __uint_as_float(rv.x & 0xFFFF0000u);
            a2 += wt * __uint_as_float(rv.y << 16);
            a3 += wt * __uint_as_float(rv.y & 0xFFFF0000u);
            a4 += wt * __uint_as_float(rv.z << 16);
            a5 += wt * __uint_as_float(rv.z & 0xFFFF0000u);
            a6 += wt * __uint_as_float(rv.w << 16);
            a7 += wt * __uint_as_float(rv.w & 0xFFFF0000u);
        };

        // lower z-plane (weight wz0): always in LDS
        const int vlo = (lz * RY + ly) * RX + lx;
#pragma unroll
        for (int iy = 0; iy < 2; ++iy)
#pragma unroll
            for (int ix = 0; ix < 2; ++ix)
                lds_corner(vlo + iy * RX + ix, wz0 * wys[iy] * wxs[ix]);

        // upper z-plane (weight wz1): LDS if lz<7 (plane lz+1) or top tile
        // (replicate: z1 clamps back to plane 7); else global fp32 reads.
        const int zhi = (lz < 7) ? (lz + 1) : (top_tile ? 7 : -1);
        if (zhi >= 0) {
            const int vhi = (zhi * RY + ly) * RX + lx;
#pragma unroll
            for (int iy = 0; iy < 2; ++iy)
#pragma unroll
                for (int ix = 0; ix < 2; ++ix)
                    lds_corner(vhi + iy * RX + ix, wz1 * wys[iy] * wxs[ix]);
        } else {
#pragma unroll
            for (int iy = 0; iy < 2; ++iy) {
#pragma unroll
                for (int ix = 0; ix < 2; ++ix) {
                    const float wt = wz1 * wys[iy] * wxs[ix];
                    const int gy = min(y0r + ly + iy, H - 1);
                    const int gx = min(x0r + lx + ix, W - 1);
                    const int a = (zpart | (gy << 7) | gx) * C;
                    const float4 v0 = *reinterpret_cast<const float4*>(inp + a);
                    const float4 v1 = *reinterpret_cast<const float4*>(inp + a + 4);
                    a0 += wt * v0.x;  a1 += wt * v0.y;
                    a2 += wt * v0.z;  a3 += wt * v0.w;
                    a4 += wt * v1.x;  a5 += wt * v1.y;
                    a6 += wt * v1.z;  a7 += wt * v1.w;
                }
            }
        }

        float* o = out + (long long)idx * C;
        *reinterpret_cast<float4*>(o)     = make_float4(a0, a1, a2, a3);
        *reinterpret_cast<float4*>(o + 4) = make_float4(a4, a5, a6, a7);
    };

    if (rv0) sample(r0);
    if (rv1) sample(r1);
    for (uint32_t i = s + (uint32_t)t + 512u; i < e; i += 256u)
        sample(records[i]);
}

// ---- fallback: direct kernel (if ws too small) -----------------------------
__global__ __launch_bounds__(256)
void resample_direct(const float* __restrict__ inp,
                     const float* __restrict__ coords,
                     float* __restrict__ out)
{
    const long long i = (long long)blockIdx.x * blockDim.x + threadIdx.x;
    if (i >= NPTS) return;
    const int b = (i >= PTS_PER_B) ? 1 : 0;
    const float zc = coords[3 * i + 0];
    const float yc = coords[3 * i + 1];
    const float xc = coords[3 * i + 2];
    const float fz = floorf(zc), fy = floorf(yc), fx = floorf(xc);
    const float wz1 = zc - fz, wz0 = 1.0f - wz1;
    const float wy1 = yc - fy, wy0 = 1.0f - wy1;
    const float wx1 = xc - fx, wx0 = 1.0f - wx1;
    const int z0 = clampi((int)fz, 0, D - 1);
    const int y0 = clampi((int)fy, 0, H - 1);
    const int x0 = clampi((int)fx, 0, W - 1);
    const int z1 = min(z0 + 1, D - 1);
    const int y1 = min(y0 + 1, H - 1);
    const int x1 = min(x0 + 1, W - 1);
    float4 acc_lo = make_float4(0.f, 0.f, 0.f, 0.f);
    float4 acc_hi = make_float4(0.f, 0.f, 0.f, 0.f);
    const int   zs[2]  = {z0, z1};
    const int   ys[2]  = {y0, y1};
    const int   xs[2]  = {x0, x1};
    const float wzs[2] = {wz0, wz1};
    const float wys[2] = {wy0, wy1};
    const float wxs[2] = {wx0, wx1};
#pragma unroll
    for (int iz = 0; iz < 2; ++iz)
#pragma unroll
        for (int iy = 0; iy < 2; ++iy)
#pragma unroll
            for (int ix = 0; ix < 2; ++ix) {
                const float wt = wzs[iz] * wys[iy] * wxs[ix];
                const int base = ((((b << 7) | zs[iz]) << 7 | ys[iy]) << 7 | xs[ix]) * C;
                const float4 v0 = *reinterpret_cast<const float4*>(inp + base);
                const float4 v1 = *reinterpret_cast<const float4*>(inp + base + 4);
                acc_lo.x += wt * v0.x;  acc_lo.y += wt * v0.y;
                acc_lo.z += wt * v0.z;  acc_lo.w += wt * v0.w;
                acc_hi.x += wt * v1.x;  acc_hi.y += wt * v1.y;
                acc_hi.z += wt * v1.z;  acc_hi.w += wt * v1.w;
            }
    float* o = out + i * C;
    *reinterpret_cast<float4*>(o)     = acc_lo;
    *reinterpret_cast<float4*>(o + 4) = acc_hi;
}

extern "C" void kernel_launch(void* const* d_in, const int* in_sizes, int n_in,
                              void* d_out, int out_size, void* d_ws, size_t ws_size,
                              hipStream_t stream)
{
    const float* inp    = (const float*)d_in[0];
    const float* coords = (const float*)d_in[1];
    float* out          = (float*)d_out;

    // ws: records u64[NPTS] | blockHist u16[NB_BIN*NT] | bucketBase u32[NT+1]
    //     | bucketTot u32[NT]
    const size_t rec_bytes  = (size_t)NPTS_I * sizeof(unsigned long long); // 14.2 MB
    const size_t hist_bytes = (size_t)NB_BIN * NT * sizeof(uint16_t);      //  1.8 MB
    const size_t base_bytes = (size_t)(NT + 1) * sizeof(uint32_t);
    const size_t tot_bytes  = (size_t)NT * sizeof(uint32_t);
    const size_t needed     = rec_bytes + hist_bytes + base_bytes + tot_bytes;

    if (ws_size < needed) {
        const int nblk = (NPTS_I + 255) / 256;
        resample_direct<<<nblk, 256, 0, stream>>>(inp, coords, out);
        return;
    }

    unsigned long long* records = (unsigned long long*)d_ws;
    uint16_t* blockHist  = (uint16_t*)((char*)d_ws + rec_bytes);
    uint32_t* bucketBase = (uint32_t*)((char*)d_ws + rec_bytes + hist_bytes);
    uint32_t* bucketTot  = (uint32_t*)((char*)d_ws + rec_bytes + hist_bytes + base_bytes);

    k_hist        <<<NB_BIN,   TPB_BIN, 0, stream>>>(coords, blockHist);
    k_scan_cols   <<<NT / 128, 128,     0, stream>>>(blockHist, bucketTot);
    k_scan_base   <<<1,        TPB_BIN, 0, stream>>>(bucketTot, bucketBase);
    k_scatter     <<<NB_BIN,   TPB_BIN, 0, stream>>>(coords, blockHist, bucketBase, records);
    k_sample_tiled<<<NT,       256,     0, stream>>>(inp, records, bucketBase, out);
}